// Round 10
// baseline (194.553 us; speedup 1.0000x reference)
//
#include <hip/hip_runtime.h>

#define DM   1024
#define LSEQ 1024
#define BATCH 8
#define MROWS (BATCH*LSEQ)   // 8192

typedef __attribute__((ext_vector_type(8))) short  bf16x8;
typedef __attribute__((ext_vector_type(4))) float  f32x4;
typedef __attribute__((ext_vector_type(4))) unsigned short u16x4;
typedef __attribute__((ext_vector_type(8))) unsigned short u16x8;

__device__ inline unsigned short f2bf(float f){
  unsigned u = __builtin_bit_cast(unsigned, f);
  u += 0x7fffu + ((u >> 16) & 1u);          // RNE
  return (unsigned short)(u >> 16);
}

__device__ inline void gload_lds16(const void* g, void* l){
  __builtin_amdgcn_global_load_lds(
      (const __attribute__((address_space(1))) void*)g,
      (__attribute__((address_space(3))) void*)l,
      16, 0, 0);
}

// ================= 128x32-tile helpers (scores / pv — proven R4 path) ======
__device__ inline void stage_gload(const unsigned short* src, int row0, int k0,
                                   unsigned short* lds, int wave, int lane)
{
  int fr = lane & 15, kg = lane >> 4;
  #pragma unroll
  for (int it = 0; it < 2; ++it){
    int nb = it*4 + wave;                 // wave-uniform
    gload_lds16(src + (size_t)(row0 + nb*16 + fr)*1024 + k0 + kg*8,
                lds + nb*512);
  }
}

__device__ inline void mma_step(const unsigned short* As, const unsigned short* Bs,
                                int wrb4, int wcb4, int fr, int kg,
                                f32x4 acc[4][4])
{
  bf16x8 av[4], bv[4];
  #pragma unroll
  for (int mi = 0; mi < 4; ++mi)
    av[mi] = *(const bf16x8*)(As + (size_t)(((wrb4 + mi)*4 + kg)*16 + fr)*8);
  #pragma unroll
  for (int ni = 0; ni < 4; ++ni)
    bv[ni] = *(const bf16x8*)(Bs + (size_t)(((wcb4 + ni)*4 + kg)*16 + fr)*8);
  #pragma unroll
  for (int mi = 0; mi < 4; ++mi)
    #pragma unroll
    for (int ni = 0; ni < 4; ++ni)
      acc[mi][ni] = __builtin_amdgcn_mfma_f32_16x16x32_bf16(av[mi], bv[ni], acc[mi][ni], 0, 0, 0);
}

// depth-3 ring (R4, proven): ONE raw barrier per K-step, counted vmcnt.
__device__ inline void gemm_ring(const unsigned short* __restrict__ A, int m0,
                                 const unsigned short* __restrict__ B, int n0,
                                 unsigned short* smem, int nk,
                                 int wave, int lane,
                                 int wrb4, int wcb4, int fr, int kg,
                                 f32x4 acc[4][4])
{
  stage_gload(A, m0, 0,  smem,        wave, lane);
  stage_gload(B, n0, 0,  smem + 4096, wave, lane);
  stage_gload(A, m0, 32, smem + 8192, wave, lane);
  stage_gload(B, n0, 32, smem + 8192 + 4096, wave, lane);
  for (int kt = 0; kt < nk; ++kt){
    if (kt + 1 < nk) asm volatile("s_waitcnt vmcnt(4)\n\ts_barrier" ::: "memory");
    else             asm volatile("s_waitcnt vmcnt(0)\n\ts_barrier" ::: "memory");
    unsigned short* buf = smem + (unsigned)(kt % 3) * 8192;
    mma_step(buf, buf + 4096, wrb4, wcb4, fr, kg, acc);
    if (kt + 2 < nk){
      unsigned short* nb = smem + (unsigned)((kt + 2) % 3) * 8192;
      stage_gload(A, m0, (kt+2)*32, nb,        wave, lane);
      stage_gload(B, n0, (kt+2)*32, nb + 4096, wave, lane);
    }
  }
}

// ---------------- X fp32 -> bf16 bulk convert ----------------
__global__ __launch_bounds__(256) void k_cvt(
    const float* __restrict__ X0, const float* __restrict__ X1, const float* __restrict__ X2,
    unsigned short* __restrict__ Y0, unsigned short* __restrict__ Y1, unsigned short* __restrict__ Y2)
{
  int z = blockIdx.z;
  const float* X = z==0 ? X0 : (z==1 ? X1 : X2);
  unsigned short* Y = z==0 ? Y0 : (z==1 ? Y1 : Y2);
  size_t i = ((size_t)blockIdx.x*256 + threadIdx.x)*8;
  f32x4 a = *(const f32x4*)(X+i);
  f32x4 b = *(const f32x4*)(X+i+4);
  u16x8 o;
  o[0]=f2bf(a[0]); o[1]=f2bf(a[1]); o[2]=f2bf(a[2]); o[3]=f2bf(a[3]);
  o[4]=f2bf(b[0]); o[5]=f2bf(b[1]); o[6]=f2bf(b[2]); o[7]=f2bf(b[3]);
  *(u16x8*)(Y+i) = o;
}

// ---------------- W transpose + convert:  Wt[n][k] = bf16(W[k][n]) ----------------
__global__ __launch_bounds__(256) void k_transpose_w(
    const float* __restrict__ W0, const float* __restrict__ W1, const float* __restrict__ W2,
    unsigned short* __restrict__ T0, unsigned short* __restrict__ T1, unsigned short* __restrict__ T2)
{
  __shared__ unsigned short tile[64*68];
  int z = blockIdx.z;
  const float* W = z==0 ? W0 : (z==1 ? W1 : W2);
  unsigned short* T = z==0 ? T0 : (z==1 ? T1 : T2);
  int n0 = blockIdx.x*64, k0 = blockIdx.y*64;
  int tid = threadIdx.x;
  {
    int r = tid >> 4;                 // 0..15
    int c = (tid & 15) * 4;
    #pragma unroll
    for (int it = 0; it < 4; ++it){
      f32x4 v = *(const f32x4*)(W + (size_t)(k0 + it*16 + r)*DM + n0 + c);
      u16x4 h; h[0]=f2bf(v[0]); h[1]=f2bf(v[1]); h[2]=f2bf(v[2]); h[3]=f2bf(v[3]);
      *(u16x4*)(tile + (it*16 + r)*68 + c) = h;
    }
  }
  __syncthreads();
  {
    int nl = tid >> 2;                // 0..63
    int kc = (tid & 3) * 16;
    u16x8 o;
    #pragma unroll
    for (int j = 0; j < 8; ++j) o[j] = tile[(kc+j)*68 + nl];
    *(u16x8*)(T + (size_t)(n0+nl)*DM + k0 + kc) = o;
    #pragma unroll
    for (int j = 0; j < 8; ++j) o[j] = tile[(kc+8+j)*68 + nl];
    *(u16x8*)(T + (size_t)(n0+nl)*DM + k0 + kc + 8) = o;
  }
}

// ================= projection GEMM: BM=256 BN=256 BK=64, 8 waves ============
// wave grid 2M x 4N, per-wave 128x64 (acc 8x4). Fragment-major LDS:
//   buf b at smem + b*32768 (shorts):
//     A chunks [idx=ks*16+nb] @ idx*512        (nb = 16-row block, ks = k-half)
//     B chunks same           @ 16384 + idx*512
// Schedule per K-tile t: {vmcnt(0); s_barrier} -> issue ALL 8 gloads of tile
// t+1 into buf^1 (full-tile latency cover) -> 2x{ 12 ds_reads + 32 MFMA }.
// No per-phase barriers: waves skew -> LDS reads overlap other waves' MFMAs.

__global__ __launch_bounds__(512, 2) void k_proj(
    const unsigned short* __restrict__ X0, const unsigned short* __restrict__ X1, const unsigned short* __restrict__ X2,
    const unsigned short* __restrict__ W0, const unsigned short* __restrict__ W1, const unsigned short* __restrict__ W2,
    unsigned short* __restrict__ qo, unsigned short* __restrict__ ko, unsigned short* __restrict__ vT)
{
  __shared__ __align__(16) unsigned short smem[65536];     // 128 KB: 2 bufs
  int z = blockIdx.z;
  const unsigned short* X  = z==0 ? X0 : (z==1 ? X1 : X2);
  const unsigned short* Wt = z==0 ? W0 : (z==1 ? W1 : W2);
  // 128 blocks/z = 32 M-tiles x 4 N-tiles; XCD-chunked swizzle (128%8==0)
  int bid = blockIdx.x;
  int t8  = (bid & 7)*16 + (bid >> 3);
  int mt  = t8 >> 2, nt = t8 & 3;
  int m0 = mt*256, n0 = nt*256;
  int tid = threadIdx.x, wave = tid >> 6, lane = tid & 63;
  int wr = wave >> 2, wc = wave & 3;                       // 2M x 4N
  int fr = lane & 15, kg = lane >> 4;
  int frkg = kg*128 + fr*8;

  // staging: 8 chunks/wave/tile: i<4 -> A chunk idx=wave+8i; i>=4 -> B
  const unsigned short* pg[8];
  int lo[8];
  #pragma unroll
  for (int i = 0; i < 4; ++i){
    int idx = wave + 8*i, ks = idx >> 4, nb = idx & 15;
    pg[i] = X + (size_t)(m0 + nb*16 + fr)*1024 + ks*32 + kg*8;
    lo[i] = idx*512;
  }
  #pragma unroll
  for (int i = 4; i < 8; ++i){
    int idx = wave + 8*(i-4), ks = idx >> 4, nb = idx & 15;
    pg[i] = Wt + (size_t)(n0 + nb*16 + fr)*1024 + ks*32 + kg*8;
    lo[i] = 16384 + idx*512;
  }

  f32x4 acc[8][4] = {};

  #pragma unroll
  for (int i = 0; i < 8; ++i) gload_lds16(pg[i], smem + lo[i]);   // tile 0 -> buf0

  #pragma unroll
  for (int t = 0; t < 16; ++t){
    const int CUR = (t & 1) ? 32768 : 0;
    const int NXT = (t & 1) ? 0 : 32768;
    asm volatile("s_waitcnt vmcnt(0)\n\ts_barrier" ::: "memory");   // tile t staged; buf NXT free
    if (t + 1 < 16){
      #pragma unroll
      for (int i = 0; i < 8; ++i)
        gload_lds16(pg[i] + (t+1)*64, smem + NXT + lo[i]);          // issue-early: full-tile cover
    }
    #pragma unroll
    for (int ks = 0; ks < 2; ++ks){
      bf16x8 av[8], bv[4];
      #pragma unroll
      for (int mi = 0; mi < 8; ++mi)
        av[mi] = *(const bf16x8*)(smem + CUR + (ks*16 + wr*8 + mi)*512 + frkg);
      #pragma unroll
      for (int ni = 0; ni < 4; ++ni)
        bv[ni] = *(const bf16x8*)(smem + CUR + 16384 + (ks*16 + wc*4 + ni)*512 + frkg);
      __builtin_amdgcn_s_setprio(1);
      #pragma unroll
      for (int mi = 0; mi < 8; ++mi)
        #pragma unroll
        for (int ni = 0; ni < 4; ++ni)
          acc[mi][ni] = __builtin_amdgcn_mfma_f32_16x16x32_bf16(av[mi], bv[ni], acc[mi][ni], 0, 0, 0);
      __builtin_amdgcn_s_setprio(0);
    }
  }

  if (z < 2){
    unsigned short* outp = (z == 0) ? qo : ko;
    #pragma unroll
    for (int mi = 0; mi < 8; ++mi)
      #pragma unroll
      for (int ni = 0; ni < 4; ++ni){
        int r = m0 + wr*128 + mi*16 + kg*4;
        int c = n0 + wc*64 + ni*16 + fr;
        #pragma unroll
        for (int i = 0; i < 4; ++i)
          outp[(size_t)(r+i)*DM + c] = f2bf(acc[mi][ni][i]);
      }
  } else {
    // transpose 256x256 tile to vT[B][D][L], in two 128-d halves via LDS
    unsigned short* Tt = smem;                        // [128][264]
    int b = m0 >> 10, l0 = m0 & 1023;
    #pragma unroll
    for (int h = 0; h < 2; ++h){
      __syncthreads();
      if ((wc >> 1) == h){
        #pragma unroll
        for (int mi = 0; mi < 8; ++mi)
          #pragma unroll
          for (int ni = 0; ni < 4; ++ni){
            int d2 = (wc & 1)*64 + ni*16 + fr;        // 0..127 within half
            int l  = wr*128 + mi*16 + kg*4;           // 0..255
            u16x4 tq;
            tq[0]=f2bf(acc[mi][ni][0]); tq[1]=f2bf(acc[mi][ni][1]);
            tq[2]=f2bf(acc[mi][ni][2]); tq[3]=f2bf(acc[mi][ni][3]);
            *(u16x4*)(Tt + d2*264 + l) = tq;
          }
      }
      __syncthreads();
      int dd = tid >> 2, ch = tid & 3;                // 128 rows x 4 chunks
      unsigned short* dst = vT + ((size_t)b << 20) + (size_t)(n0 + h*128 + dd)*LSEQ + l0 + ch*64;
      const unsigned short* srcT = Tt + dd*264 + ch*64;
      #pragma unroll
      for (int k = 0; k < 8; ++k)
        *(u16x8*)(dst + k*8) = *(const u16x8*)(srcT + k*8);
    }
  }
}

// ---------------- scores: S = (q.k)/32, causal block-skip, ring3 (R4) -------
__global__ __launch_bounds__(256) void k_scores(
    const unsigned short* __restrict__ q, const unsigned short* __restrict__ k,
    float* __restrict__ S)
{
  __shared__ __align__(16) unsigned short smem[24576];
  int b = blockIdx.z;
  int raw = blockIdx.x + 8*blockIdx.y;
  int tile = (raw & 7)*8 + (raw >> 3);
  int kt = tile & 7, qt = tile >> 3;
  if (kt > qt) return;                               // block-uniform exit
  const unsigned short* qb = q + ((size_t)b << 20);
  const unsigned short* kb = k + ((size_t)b << 20);
  int m0 = qt*128, n0 = kt*128;
  int tid = threadIdx.x, wave = tid >> 6, lane = tid & 63;
  int wrb4 = (wave >> 1)*4, wcb4 = (wave & 1)*4, fr = lane & 15, kg = lane >> 4;
  f32x4 acc[4][4] = {};
  gemm_ring(qb, m0, kb, n0, smem, 32, wave, lane, wrb4, wcb4, fr, kg, acc);

  float* Sb = S + ((size_t)b << 20);
  const float scale = 0.03125f;                      // 1/sqrt(1024)
  #pragma unroll
  for (int mi = 0; mi < 4; ++mi)
    #pragma unroll
    for (int ni = 0; ni < 4; ++ni){
      int r = m0 + wrb4*16 + mi*16 + kg*4;
      int c = n0 + wcb4*16 + ni*16 + fr;
      #pragma unroll
      for (int i = 0; i < 4; ++i)
        Sb[(size_t)(r+i)*LSEQ + c] = acc[mi][ni][i] * scale;
    }
}

// ---------------- causal row softmax: P bf16, zeros above diagonal ----------------
__global__ __launch_bounds__(256) void k_softmax(
    const float* __restrict__ S, unsigned short* __restrict__ P)
{
  int gq = blockIdx.x;                                // 0..8191
  int qq = gq & 1023;
  const float* row = S + (size_t)gq * 1024;
  unsigned short* prow = P + (size_t)gq * 1024;
  int tid = threadIdx.x;

  f32x4 v = *(const f32x4*)(row + tid*4);
  float vals[4];
  float m = -1e30f;
  #pragma unroll
  for (int e = 0; e < 4; ++e){
    int idx = tid*4 + e;
    vals[e] = (idx <= qq) ? v[e] : -1e30f;
    m = fmaxf(m, vals[e]);
  }
  #pragma unroll
  for (int off = 32; off >= 1; off >>= 1) m = fmaxf(m, __shfl_xor(m, off));
  __shared__ float redm[4], reds[4];
  if ((tid & 63) == 0) redm[tid >> 6] = m;
  __syncthreads();
  m = fmaxf(fmaxf(redm[0], redm[1]), fmaxf(redm[2], redm[3]));

  float e4[4], s = 0.f;
  #pragma unroll
  for (int e = 0; e < 4; ++e){
    int idx = tid*4 + e;
    e4[e] = (idx <= qq) ? __expf(vals[e] - m) : 0.f;
    s += e4[e];
  }
  #pragma unroll
  for (int off = 32; off >= 1; off >>= 1) s += __shfl_xor(s, off);
  if ((tid & 63) == 0) reds[tid >> 6] = s;
  __syncthreads();
  s = reds[0] + reds[1] + reds[2] + reds[3];
  float inv = 1.f / s;

  u16x4 o;
  #pragma unroll
  for (int e = 0; e < 4; ++e) o[e] = f2bf(e4[e] * inv);
  *(u16x4*)(prow + tid*4) = o;
}

// ---------------- PV: O = P @ vT^T, diag-cut K, ring3 (R4) ----------------
__global__ __launch_bounds__(256) void k_pv(
    const unsigned short* __restrict__ P, const unsigned short* __restrict__ vT,
    float* __restrict__ O)
{
  __shared__ __align__(16) unsigned short smem[24576];
  int b = blockIdx.z;
  int raw = blockIdx.x + 8*blockIdx.y;
  int tile = (raw & 7)*8 + (raw >> 3);
  int dt = tile & 7, qt = tile >> 3;
  const unsigned short* Pb = P  + ((size_t)b << 20);
  const unsigned short* Vb = vT + ((size_t)b << 20);
  int m0 = qt*128, n0 = dt*128;
  int tid = threadIdx.x, wave = tid >> 6, lane = tid & 63;
  int wrb4 = (wave >> 1)*4, wcb4 = (wave & 1)*4, fr = lane & 15, kg = lane >> 4;
  f32x4 acc[4][4] = {};
  int nk = (qt + 1) * 4;                              // kk in [0,(qt+1)*128); >= 4
  gemm_ring(Pb, m0, Vb, n0, smem, nk, wave, lane, wrb4, wcb4, fr, kg, acc);

  float* Ob = O + ((size_t)(b*1024 + m0) << 10);
  #pragma unroll
  for (int mi = 0; mi < 4; ++mi)
    #pragma unroll
    for (int ni = 0; ni < 4; ++ni){
      int r = wrb4*16 + mi*16 + kg*4;
      int c = n0 + wcb4*16 + ni*16 + fr;
      #pragma unroll
      for (int i = 0; i < 4; ++i)
        Ob[(size_t)(r+i)*DM + c] = acc[mi][ni][i];
    }
}

extern "C" void kernel_launch(void* const* d_in, const int* in_sizes, int n_in,
                              void* d_out, int out_size, void* d_ws, size_t ws_size,
                              hipStream_t stream)
{
  const float* query = (const float*)d_in[0];
  const float* key   = (const float*)d_in[1];
  const float* value = (const float*)d_in[2];
  const float* Wq    = (const float*)d_in[3];
  const float* Wk    = (const float*)d_in[4];
  const float* Wv    = (const float*)d_in[5];
  float* out = (float*)d_out;

  unsigned short* ws = (unsigned short*)d_ws;
  unsigned short* qb  = ws;                                   // 8192x1024 bf16
  unsigned short* kb  = qb  + (size_t)MROWS*DM;
  unsigned short* vT  = kb  + (size_t)MROWS*DM;               // [B][D][L]
  unsigned short* WqT = vT  + (size_t)MROWS*DM;               // [N][K] bf16
  unsigned short* WkT = WqT + (size_t)DM*DM;
  unsigned short* WvT = WkT + (size_t)DM*DM;
  unsigned short* P   = WvT + (size_t)DM*DM;                  // [B][L][L] bf16

  // Dead-buffer reuse:
  //   Xq,Xk (bf16) live in d_out until k_scores overwrites it with S.
  //   Xv (bf16) lives in the P region until k_softmax overwrites it with P.
  unsigned short* outU = (unsigned short*)d_out;
  unsigned short* Xq = outU;                                  // 8M bf16 = 16 MB
  unsigned short* Xk = outU + (size_t)MROWS*DM;               // 8M bf16 = 16 MB
  unsigned short* Xv = P;                                     // 8M bf16 = 16 MB
  float* S = out;                                             // scores fp32 in d_out

  dim3 blk(256);
  k_transpose_w<<<dim3(16,16,3), blk, 0, stream>>>(Wq, Wk, Wv, WqT, WkT, WvT);
  k_cvt        <<<dim3(4096,1,3), blk, 0, stream>>>(query, key, value, Xq, Xk, Xv);
  k_proj       <<<dim3(128,1,3), dim3(512), 0, stream>>>(Xq, Xk, Xv, WqT, WkT, WvT, qb, kb, vT);
  k_scores     <<<dim3(8,8,8),   blk, 0, stream>>>(qb, kb, S);
  k_softmax    <<<dim3(8192),    blk, 0, stream>>>(S, P);
  k_pv         <<<dim3(8,8,8),   blk, 0, stream>>>(P, vT, out);
}

// Round 11
// 185.401 us; speedup vs baseline: 1.0494x; 1.0494x over previous
//
#include <hip/hip_runtime.h>

#define DM   1024
#define LSEQ 1024
#define BATCH 8
#define MROWS (BATCH*LSEQ)   // 8192

typedef __attribute__((ext_vector_type(8))) short  bf16x8;
typedef __attribute__((ext_vector_type(4))) float  f32x4;
typedef __attribute__((ext_vector_type(4))) unsigned short u16x4;
typedef __attribute__((ext_vector_type(8))) unsigned short u16x8;

__device__ inline unsigned short f2bf(float f){
  unsigned u = __builtin_bit_cast(unsigned, f);
  u += 0x7fffu + ((u >> 16) & 1u);          // RNE
  return (unsigned short)(u >> 16);
}

__device__ inline void gload_lds16(const void* g, void* l){
  __builtin_amdgcn_global_load_lds(
      (const __attribute__((address_space(1))) void*)g,
      (__attribute__((address_space(3))) void*)l,
      16, 0, 0);
}

// ================= 128x32-tile helpers (scores / pv — proven R4 path) ======
__device__ inline void stage_gload(const unsigned short* src, int row0, int k0,
                                   unsigned short* lds, int wave, int lane)
{
  int fr = lane & 15, kg = lane >> 4;
  #pragma unroll
  for (int it = 0; it < 2; ++it){
    int nb = it*4 + wave;                 // wave-uniform
    gload_lds16(src + (size_t)(row0 + nb*16 + fr)*1024 + k0 + kg*8,
                lds + nb*512);
  }
}

__device__ inline void mma_step(const unsigned short* As, const unsigned short* Bs,
                                int wrb4, int wcb4, int fr, int kg,
                                f32x4 acc[4][4])
{
  bf16x8 av[4], bv[4];
  #pragma unroll
  for (int mi = 0; mi < 4; ++mi)
    av[mi] = *(const bf16x8*)(As + (size_t)(((wrb4 + mi)*4 + kg)*16 + fr)*8);
  #pragma unroll
  for (int ni = 0; ni < 4; ++ni)
    bv[ni] = *(const bf16x8*)(Bs + (size_t)(((wcb4 + ni)*4 + kg)*16 + fr)*8);
  #pragma unroll
  for (int mi = 0; mi < 4; ++mi)
    #pragma unroll
    for (int ni = 0; ni < 4; ++ni)
      acc[mi][ni] = __builtin_amdgcn_mfma_f32_16x16x32_bf16(av[mi], bv[ni], acc[mi][ni], 0, 0, 0);
}

// depth-3 ring (R4, proven): ONE raw barrier per K-step, counted vmcnt.
__device__ inline void gemm_ring(const unsigned short* __restrict__ A, int m0,
                                 const unsigned short* __restrict__ B, int n0,
                                 unsigned short* smem, int nk,
                                 int wave, int lane,
                                 int wrb4, int wcb4, int fr, int kg,
                                 f32x4 acc[4][4])
{
  stage_gload(A, m0, 0,  smem,        wave, lane);
  stage_gload(B, n0, 0,  smem + 4096, wave, lane);
  stage_gload(A, m0, 32, smem + 8192, wave, lane);
  stage_gload(B, n0, 32, smem + 8192 + 4096, wave, lane);
  for (int kt = 0; kt < nk; ++kt){
    if (kt + 1 < nk) asm volatile("s_waitcnt vmcnt(4)\n\ts_barrier" ::: "memory");
    else             asm volatile("s_waitcnt vmcnt(0)\n\ts_barrier" ::: "memory");
    unsigned short* buf = smem + (unsigned)(kt % 3) * 8192;
    mma_step(buf, buf + 4096, wrb4, wcb4, fr, kg, acc);
    if (kt + 2 < nk){
      unsigned short* nb = smem + (unsigned)((kt + 2) % 3) * 8192;
      stage_gload(A, m0, (kt+2)*32, nb,        wave, lane);
      stage_gload(B, n0, (kt+2)*32, nb + 4096, wave, lane);
    }
  }
}

// ---------------- X fp32 -> bf16 bulk convert ----------------
__global__ __launch_bounds__(256) void k_cvt(
    const float* __restrict__ X0, const float* __restrict__ X1, const float* __restrict__ X2,
    unsigned short* __restrict__ Y0, unsigned short* __restrict__ Y1, unsigned short* __restrict__ Y2)
{
  int z = blockIdx.z;
  const float* X = z==0 ? X0 : (z==1 ? X1 : X2);
  unsigned short* Y = z==0 ? Y0 : (z==1 ? Y1 : Y2);
  size_t i = ((size_t)blockIdx.x*256 + threadIdx.x)*8;
  f32x4 a = *(const f32x4*)(X+i);
  f32x4 b = *(const f32x4*)(X+i+4);
  u16x8 o;
  o[0]=f2bf(a[0]); o[1]=f2bf(a[1]); o[2]=f2bf(a[2]); o[3]=f2bf(a[3]);
  o[4]=f2bf(b[0]); o[5]=f2bf(b[1]); o[6]=f2bf(b[2]); o[7]=f2bf(b[3]);
  *(u16x8*)(Y+i) = o;
}

// ---------------- W transpose + convert:  Wt[n][k] = bf16(W[k][n]) ----------------
__global__ __launch_bounds__(256) void k_transpose_w(
    const float* __restrict__ W0, const float* __restrict__ W1, const float* __restrict__ W2,
    unsigned short* __restrict__ T0, unsigned short* __restrict__ T1, unsigned short* __restrict__ T2)
{
  __shared__ unsigned short tile[64*68];
  int z = blockIdx.z;
  const float* W = z==0 ? W0 : (z==1 ? W1 : W2);
  unsigned short* T = z==0 ? T0 : (z==1 ? T1 : T2);
  int n0 = blockIdx.x*64, k0 = blockIdx.y*64;
  int tid = threadIdx.x;
  {
    int r = tid >> 4;                 // 0..15
    int c = (tid & 15) * 4;
    #pragma unroll
    for (int it = 0; it < 4; ++it){
      f32x4 v = *(const f32x4*)(W + (size_t)(k0 + it*16 + r)*DM + n0 + c);
      u16x4 h; h[0]=f2bf(v[0]); h[1]=f2bf(v[1]); h[2]=f2bf(v[2]); h[3]=f2bf(v[3]);
      *(u16x4*)(tile + (it*16 + r)*68 + c) = h;
    }
  }
  __syncthreads();
  {
    int nl = tid >> 2;                // 0..63
    int kc = (tid & 3) * 16;
    u16x8 o;
    #pragma unroll
    for (int j = 0; j < 8; ++j) o[j] = tile[(kc+j)*68 + nl];
    *(u16x8*)(T + (size_t)(n0+nl)*DM + k0 + kc) = o;
    #pragma unroll
    for (int j = 0; j < 8; ++j) o[j] = tile[(kc+8+j)*68 + nl];
    *(u16x8*)(T + (size_t)(n0+nl)*DM + k0 + kc + 8) = o;
  }
}

// ================= projection GEMM: BM=256 BN=256 BK=64, 8 waves ============
// 8-phase-style schedule with K-SPLIT units (counted vmcnt, never 0 mid-loop):
//   unit (t,u): u0=A-ks0, u1=B-ks0, u2=A-ks1, u3=B-ks1; each 256rows x 32K
//   = 16 chunks of [16 rows frag-major] = 8192 shorts. LDS slot (t&1)*4+u.
//   8 slots x 16 KB = 128 KB.
// Phase p of tile t: (ks=p>>1, mh=p&1): 8 ds_reads + 16 MFMA; stages unit p
// of tile t+1 (opposite parity -> no write/read overlap by construction).
// Consumption ordered by ks -> vmcnt(4) at p0/p2 suffices (units in flight
// get 3-4 phases of latency cover).

#define VM4  asm volatile("s_waitcnt vmcnt(4)" ::: "memory")
#define VM0  asm volatile("s_waitcnt vmcnt(0)" ::: "memory")

#define STAGE_U(tt, u) do{ \
  unsigned qq_ = (unsigned)(((tt)&1)*32768 + (u)*8192); \
  int koff_ = (tt)*64 + ((u)>>1)*32; \
  if (((u)&1)==0){ \
    gload_lds16(pa0 + koff_, smem + qq_ + wave*512); \
    gload_lds16(pa1 + koff_, smem + qq_ + (wave+8)*512); \
  } else { \
    gload_lds16(pb0 + koff_, smem + qq_ + wave*512); \
    gload_lds16(pb1 + koff_, smem + qq_ + (wave+8)*512); \
  } }while(0)

#define PHASE(tt, p, DOSTAGE, VMW) do{ \
  VMW; \
  asm volatile("s_barrier" ::: "memory"); \
  const int ks_ = (p)>>1, mh_ = (p)&1; \
  unsigned qb_ = (unsigned)(((tt)&1)*32768); \
  const unsigned short* Au_ = smem + qb_ + (ks_*2+0)*8192; \
  const unsigned short* Bu_ = smem + qb_ + (ks_*2+1)*8192; \
  bf16x8 av_[4], bv_[4]; \
  _Pragma("unroll") for (int mi=0;mi<4;++mi) \
    av_[mi] = *(const bf16x8*)(Au_ + (wr*8 + mh_*4 + mi)*512 + frkg); \
  _Pragma("unroll") for (int ni=0;ni<4;++ni) \
    bv_[ni] = *(const bf16x8*)(Bu_ + (wc*4 + ni)*512 + frkg); \
  if (DOSTAGE) STAGE_U((tt)+1, p); \
  asm volatile("s_barrier" ::: "memory"); \
  asm volatile("s_waitcnt lgkmcnt(0)" ::: "memory"); \
  __builtin_amdgcn_s_setprio(1); \
  _Pragma("unroll") for (int mi=0;mi<4;++mi) \
    _Pragma("unroll") for (int ni=0;ni<4;++ni) \
      acc[mh_*4+mi][ni] = __builtin_amdgcn_mfma_f32_16x16x32_bf16(av_[mi], bv_[ni], acc[mh_*4+mi][ni], 0, 0, 0); \
  __builtin_amdgcn_s_setprio(0); \
}while(0)

__global__ __launch_bounds__(512, 2) void k_proj(
    const unsigned short* __restrict__ X0, const unsigned short* __restrict__ X1, const unsigned short* __restrict__ X2,
    const unsigned short* __restrict__ W0, const unsigned short* __restrict__ W1, const unsigned short* __restrict__ W2,
    unsigned short* __restrict__ qo, unsigned short* __restrict__ ko, unsigned short* __restrict__ vT)
{
  __shared__ __align__(16) unsigned short smem[65536];     // 128 KB: 8 unit slots
  int z = blockIdx.z;
  const unsigned short* X  = z==0 ? X0 : (z==1 ? X1 : X2);
  const unsigned short* Wt = z==0 ? W0 : (z==1 ? W1 : W2);
  // 128 blocks/z = 32 M-tiles x 4 N-tiles; XCD-chunked swizzle (128%8==0)
  int bid = blockIdx.x;
  int t8  = (bid & 7)*16 + (bid >> 3);
  int mt  = t8 >> 2, nt = t8 & 3;
  int m0 = mt*256, n0 = nt*256;
  int tid = threadIdx.x, wave = tid >> 6, lane = tid & 63;
  int wr = wave >> 2, wc = wave & 3;                       // 2M x 4N
  int fr = lane & 15, kg = lane >> 4;
  int frkg = kg*128 + fr*8;

  // staging source pointers (chunk nb = wave and wave+8 per unit)
  const unsigned short* pa0 = X  + (size_t)(m0 + wave*16 + fr)*1024 + kg*8;
  const unsigned short* pa1 = pa0 + (size_t)128*1024;
  const unsigned short* pb0 = Wt + (size_t)(n0 + wave*16 + fr)*1024 + kg*8;
  const unsigned short* pb1 = pb0 + (size_t)128*1024;

  f32x4 acc[8][4] = {};

  // prologue: 4 units of tile 0
  STAGE_U(0,0); STAGE_U(0,1); STAGE_U(0,2); STAGE_U(0,3);

  for (int t = 0; t < 15; ++t){
    PHASE(t, 0, true, VM4);
    PHASE(t, 1, true, );
    PHASE(t, 2, true, VM4);
    PHASE(t, 3, true, );
  }
  PHASE(15, 0, false, VM4);
  PHASE(15, 1, false, );
  PHASE(15, 2, false, VM0);
  PHASE(15, 3, false, );

  if (z < 2){
    unsigned short* outp = (z == 0) ? qo : ko;
    #pragma unroll
    for (int mi = 0; mi < 8; ++mi)
      #pragma unroll
      for (int ni = 0; ni < 4; ++ni){
        int r = m0 + wr*128 + mi*16 + kg*4;
        int c = n0 + wc*64 + ni*16 + fr;
        #pragma unroll
        for (int i = 0; i < 4; ++i)
          outp[(size_t)(r+i)*DM + c] = f2bf(acc[mi][ni][i]);
      }
  } else {
    // transpose 256x256 tile to vT[B][D][L], in two 128-d halves via LDS
    unsigned short* Tt = smem;                        // [128][264]
    int b = m0 >> 10, l0 = m0 & 1023;
    #pragma unroll
    for (int h = 0; h < 2; ++h){
      __syncthreads();
      if ((wc >> 1) == h){
        #pragma unroll
        for (int mi = 0; mi < 8; ++mi)
          #pragma unroll
          for (int ni = 0; ni < 4; ++ni){
            int d2 = (wc & 1)*64 + ni*16 + fr;        // 0..127 within half
            int l  = wr*128 + mi*16 + kg*4;           // 0..255
            u16x4 tq;
            tq[0]=f2bf(acc[mi][ni][0]); tq[1]=f2bf(acc[mi][ni][1]);
            tq[2]=f2bf(acc[mi][ni][2]); tq[3]=f2bf(acc[mi][ni][3]);
            *(u16x4*)(Tt + d2*264 + l) = tq;
          }
      }
      __syncthreads();
      int dd = tid >> 2, ch = tid & 3;                // 128 rows x 4 chunks
      unsigned short* dst = vT + ((size_t)b << 20) + (size_t)(n0 + h*128 + dd)*LSEQ + l0 + ch*64;
      const unsigned short* srcT = Tt + dd*264 + ch*64;
      #pragma unroll
      for (int k = 0; k < 8; ++k)
        *(u16x8*)(dst + k*8) = *(const u16x8*)(srcT + k*8);
    }
  }
}

// ---------------- scores: S = (q.k)/32, causal block-skip, ring3 (R4) -------
__global__ __launch_bounds__(256) void k_scores(
    const unsigned short* __restrict__ q, const unsigned short* __restrict__ k,
    float* __restrict__ S)
{
  __shared__ __align__(16) unsigned short smem[24576];
  int b = blockIdx.z;
  int raw = blockIdx.x + 8*blockIdx.y;
  int tile = (raw & 7)*8 + (raw >> 3);
  int kt = tile & 7, qt = tile >> 3;
  if (kt > qt) return;                               // block-uniform exit
  const unsigned short* qb = q + ((size_t)b << 20);
  const unsigned short* kb = k + ((size_t)b << 20);
  int m0 = qt*128, n0 = kt*128;
  int tid = threadIdx.x, wave = tid >> 6, lane = tid & 63;
  int wrb4 = (wave >> 1)*4, wcb4 = (wave & 1)*4, fr = lane & 15, kg = lane >> 4;
  f32x4 acc[4][4] = {};
  gemm_ring(qb, m0, kb, n0, smem, 32, wave, lane, wrb4, wcb4, fr, kg, acc);

  float* Sb = S + ((size_t)b << 20);
  const float scale = 0.03125f;                      // 1/sqrt(1024)
  #pragma unroll
  for (int mi = 0; mi < 4; ++mi)
    #pragma unroll
    for (int ni = 0; ni < 4; ++ni){
      int r = m0 + wrb4*16 + mi*16 + kg*4;
      int c = n0 + wcb4*16 + ni*16 + fr;
      #pragma unroll
      for (int i = 0; i < 4; ++i)
        Sb[(size_t)(r+i)*LSEQ + c] = acc[mi][ni][i] * scale;
    }
}

// ---------------- causal row softmax: P bf16, zeros above diagonal ----------------
__global__ __launch_bounds__(256) void k_softmax(
    const float* __restrict__ S, unsigned short* __restrict__ P)
{
  int gq = blockIdx.x;                                // 0..8191
  int qq = gq & 1023;
  const float* row = S + (size_t)gq * 1024;
  unsigned short* prow = P + (size_t)gq * 1024;
  int tid = threadIdx.x;

  f32x4 v = *(const f32x4*)(row + tid*4);
  float vals[4];
  float m = -1e30f;
  #pragma unroll
  for (int e = 0; e < 4; ++e){
    int idx = tid*4 + e;
    vals[e] = (idx <= qq) ? v[e] : -1e30f;
    m = fmaxf(m, vals[e]);
  }
  #pragma unroll
  for (int off = 32; off >= 1; off >>= 1) m = fmaxf(m, __shfl_xor(m, off));
  __shared__ float redm[4], reds[4];
  if ((tid & 63) == 0) redm[tid >> 6] = m;
  __syncthreads();
  m = fmaxf(fmaxf(redm[0], redm[1]), fmaxf(redm[2], redm[3]));

  float e4[4], s = 0.f;
  #pragma unroll
  for (int e = 0; e < 4; ++e){
    int idx = tid*4 + e;
    e4[e] = (idx <= qq) ? __expf(vals[e] - m) : 0.f;
    s += e4[e];
  }
  #pragma unroll
  for (int off = 32; off >= 1; off >>= 1) s += __shfl_xor(s, off);
  if ((tid & 63) == 0) reds[tid >> 6] = s;
  __syncthreads();
  s = reds[0] + reds[1] + reds[2] + reds[3];
  float inv = 1.f / s;

  u16x4 o;
  #pragma unroll
  for (int e = 0; e < 4; ++e) o[e] = f2bf(e4[e] * inv);
  *(u16x4*)(prow + tid*4) = o;
}

// ---------------- PV: O = P @ vT^T, diag-cut K, ring3 (R4) ----------------
__global__ __launch_bounds__(256) void k_pv(
    const unsigned short* __restrict__ P, const unsigned short* __restrict__ vT,
    float* __restrict__ O)
{
  __shared__ __align__(16) unsigned short smem[24576];
  int b = blockIdx.z;
  int raw = blockIdx.x + 8*blockIdx.y;
  int tile = (raw & 7)*8 + (raw >> 3);
  int dt = tile & 7, qt = tile >> 3;
  const unsigned short* Pb = P  + ((size_t)b << 20);
  const unsigned short* Vb = vT + ((size_t)b << 20);
  int m0 = qt*128, n0 = dt*128;
  int tid = threadIdx.x, wave = tid >> 6, lane = tid & 63;
  int wrb4 = (wave >> 1)*4, wcb4 = (wave & 1)*4, fr = lane & 15, kg = lane >> 4;
  f32x4 acc[4][4] = {};
  int nk = (qt + 1) * 4;                              // kk in [0,(qt+1)*128); >= 4
  gemm_ring(Pb, m0, Vb, n0, smem, nk, wave, lane, wrb4, wcb4, fr, kg, acc);

  float* Ob = O + ((size_t)(b*1024 + m0) << 10);
  #pragma unroll
  for (int mi = 0; mi < 4; ++mi)
    #pragma unroll
    for (int ni = 0; ni < 4; ++ni){
      int r = wrb4*16 + mi*16 + kg*4;
      int c = n0 + wcb4*16 + ni*16 + fr;
      #pragma unroll
      for (int i = 0; i < 4; ++i)
        Ob[(size_t)(r+i)*DM + c] = acc[mi][ni][i];
    }
}

extern "C" void kernel_launch(void* const* d_in, const int* in_sizes, int n_in,
                              void* d_out, int out_size, void* d_ws, size_t ws_size,
                              hipStream_t stream)
{
  const float* query = (const float*)d_in[0];
  const float* key   = (const float*)d_in[1];
  const float* value = (const float*)d_in[2];
  const float* Wq    = (const float*)d_in[3];
  const float* Wk    = (const float*)d_in[4];
  const float* Wv    = (const float*)d_in[5];
  float* out = (float*)d_out;

  unsigned short* ws = (unsigned short*)d_ws;
  unsigned short* qb  = ws;                                   // 8192x1024 bf16
  unsigned short* kb  = qb  + (size_t)MROWS*DM;
  unsigned short* vT  = kb  + (size_t)MROWS*DM;               // [B][D][L]
  unsigned short* WqT = vT  + (size_t)MROWS*DM;               // [N][K] bf16
  unsigned short* WkT = WqT + (size_t)DM*DM;
  unsigned short* WvT = WkT + (size_t)DM*DM;
  unsigned short* P   = WvT + (size_t)DM*DM;                  // [B][L][L] bf16

  // Dead-buffer reuse:
  //   Xq,Xk (bf16) live in d_out until k_scores overwrites it with S.
  //   Xv (bf16) lives in the P region until k_softmax overwrites it with P.
  unsigned short* outU = (unsigned short*)d_out;
  unsigned short* Xq = outU;                                  // 8M bf16 = 16 MB
  unsigned short* Xk = outU + (size_t)MROWS*DM;               // 8M bf16 = 16 MB
  unsigned short* Xv = P;                                     // 8M bf16 = 16 MB
  float* S = out;                                             // scores fp32 in d_out

  dim3 blk(256);
  k_transpose_w<<<dim3(16,16,3), blk, 0, stream>>>(Wq, Wk, Wv, WqT, WkT, WvT);
  k_cvt        <<<dim3(4096,1,3), blk, 0, stream>>>(query, key, value, Xq, Xk, Xv);
  k_proj       <<<dim3(128,1,3), dim3(512), 0, stream>>>(Xq, Xk, Xv, WqT, WkT, WvT, qb, kb, vT);
  k_scores     <<<dim3(8,8,8),   blk, 0, stream>>>(qb, kb, S);
  k_softmax    <<<dim3(8192),    blk, 0, stream>>>(S, P);
  k_pv         <<<dim3(8,8,8),   blk, 0, stream>>>(P, vT, out);
}